// Round 3
// baseline (272.488 us; speedup 1.0000x reference)
//
#include <hip/hip_runtime.h>
#include <math.h>

#define IM 128
#define BZ 32

typedef float v4f __attribute__((ext_vector_type(4)));

// One block per (b, v): grid = 32 * 129 = 4128 blocks, 256 threads, 1 KB LDS.
// Combines R0's occupancy (~8 blocks/CU -> 32 waves/CU of store TLP) with
// R2's store pattern (each block streams ONE contiguous 64 KB tile).
//
//   DFT:  thread (h = tid>>1, part = tid&1) reads x[b,h,part*64..+63] directly
//         from global (64 KB per block; XCD-chunked swizzle keeps all 129
//         v-blocks of a batch on one XCD so repeats are L2 hits), accumulates
//         t[v,h] = sum_w x[h,w] e^{-2pi i v w/128} via the proven in-register
//         phasor recurrence, shfl-reduces the two halves, stashes t in 1 KB LDS.
//   emit: out[b,v,h,w] = tre[h] cos(A v w) - tim[h] sin(A v w); twiddles
//         computed once per thread from exact integer k = v*w mod 128
//         (v is block-uniform, so they are loop-invariant registers).
//         Stores: 1 KB/wave, tile-sequential -- fill-kernel access pattern.
//   v==128 blocks do the contiguous passthrough copy of input[b,1,:,:].

__global__ __launch_bounds__(256) void kspace_fused(const float* __restrict__ in,
                                                    float* __restrict__ out) {
    const int g   = blockIdx.x;                        // 0..4127
    const int lin = (g & 7) * 516 + (g >> 3);          // XCD-chunked (4128%8==0)
    const int b   = (int)((unsigned)lin / 129u);
    const int v   = lin - b * 129;
    const int tid = threadIdx.x;                       // 0..255

    float* tile = out + ((size_t)b * 129 + v) * (IM * IM);

    if (v == IM) {
        // passthrough: out[b,128,:,:] = input[b,1,:,:]  (contiguous 64 KB)
        const v4f* src = (const v4f*)(in + ((size_t)b * 2 + 1) * IM * IM);
        v4f*       dst = (v4f*)tile;
        #pragma unroll
        for (int i = 0; i < 16; ++i) dst[i * 256 + tid] = src[i * 256 + tid];
        return;
    }

    const float A = 6.28318530717958647692f / (float)IM;   // 2*pi/128
    __shared__ float tre[IM], tim[IM];

    // ---- DFT: t[v,h], two 64-term halves per h ----
    {
        const int h    = tid >> 1;
        const int part = tid & 1;
        const int wb   = part << 6;                    // 0 or 64
        const float* xr = in + (size_t)b * 2 * IM * IM + (size_t)h * IM + wb;

        float pc, ps;
        { int k = (v * wb) & (IM - 1); sincosf(A * (float)k, &ps, &pc); ps = -ps; }
        float rc, rs;
        sincosf(A * (float)v, &rs, &rc); rs = -rs;     // step e^{-2pi i v/128}

        float sre = 0.0f, sim = 0.0f;
        #pragma unroll 4
        for (int i = 0; i < 16; ++i) {
            const v4f xv = *(const v4f*)(xr + 4 * i);  // L2-hit after first block
            float n;
            sre = fmaf(xv.x, pc, sre); sim = fmaf(xv.x, ps, sim);
            n = pc * rc - ps * rs; ps = fmaf(ps, rc, pc * rs); pc = n;
            sre = fmaf(xv.y, pc, sre); sim = fmaf(xv.y, ps, sim);
            n = pc * rc - ps * rs; ps = fmaf(ps, rc, pc * rs); pc = n;
            sre = fmaf(xv.z, pc, sre); sim = fmaf(xv.z, ps, sim);
            n = pc * rc - ps * rs; ps = fmaf(ps, rc, pc * rs); pc = n;
            sre = fmaf(xv.w, pc, sre); sim = fmaf(xv.w, ps, sim);
            n = pc * rc - ps * rs; ps = fmaf(ps, rc, pc * rs); pc = n;
        }
        sre += __shfl_xor(sre, 1);
        sim += __shfl_xor(sim, 1);
        if (part == 0) {
            tre[h] = sre * (1.0f / IM);                // even lanes, consecutive
            tim[h] = sim * (1.0f / IM);                //   addresses: conflict-free
        }
    }
    __syncthreads();

    // ---- emit: contiguous 64 KB tile, loop-invariant exact twiddles ----
    const int w0   = (tid & 31) * 4;                   // 0,4,...,124
    const int hsub = tid >> 5;                         // 0..7

    float cw[4], sw[4];
    #pragma unroll
    for (int j = 0; j < 4; ++j) {
        const int k = (v * (w0 + j)) & (IM - 1);       // exact k = v*w mod 128
        sincosf(A * (float)k, &sw[j], &cw[j]);
    }

    #pragma unroll
    for (int i = 0; i < 16; ++i) {
        const int h = i * 8 + hsub;
        const float re = tre[h];                       // 2-addr broadcast reads
        const float im = tim[h];
        v4f r;
        r.x = re * cw[0] - im * sw[0];
        r.y = re * cw[1] - im * sw[1];
        r.z = re * cw[2] - im * sw[2];
        r.w = re * cw[3] - im * sw[3];
        *(v4f*)(tile + (size_t)h * IM + w0) = r;       // 1 KB/wave, sequential
    }
}

extern "C" void kernel_launch(void* const* d_in, const int* in_sizes, int n_in,
                              void* d_out, int out_size, void* d_ws, size_t ws_size,
                              hipStream_t stream) {
    const float* in = (const float*)d_in[0];   // (32, 2, 128, 128) fp32; mask unused
    float* out = (float*)d_out;                // (32, 129, 128, 128) fp32
    kspace_fused<<<dim3(BZ * 129), dim3(256), 0, stream>>>(in, out);
}